// Round 17
// baseline (319.494 us; speedup 1.0000x reference)
//
#include <hip/hip_runtime.h>
#include <hip/hip_cooperative_groups.h>
#include <math.h>

namespace cg = cooperative_groups;

#define B_  16
#define F_  64
#define C_  64
#define M_  512
#define OC_ 32

typedef float vf4 __attribute__((ext_vector_type(4)));   // clang-native for nt st

// ===========================================================================
// FALLBACK PATH (R15 best-known, 65.2 us): k1 / k2 / k3
// ===========================================================================
__global__ __launch_bounds__(128, 6) void k1_mean(
    const float* __restrict__ x,
    float* __restrict__ s_out, float* __restrict__ rpart)
{
    const int gid = blockIdx.x;        // bc*4 + q
    const int q   = gid & 3;
    const int bc  = gid >> 2;
    const int b   = bc >> 6;
    const int c   = bc & 63;
    const int t   = threadIdx.x;
    const int tf  = t >> 5;
    const int tm  = t & 31;
    const int m4  = (q << 5) + tm;

    const size_t rowbase = ((size_t)b * F_ * C_ + c) * M_;
    float ax = 0.f, ay = 0.f, az = 0.f, aw = 0.f;
    #pragma unroll 8
    for (int j = 0; j < 16; ++j) {
        const int f = (tf << 4) + j;
        const float4 v = ((const float4*)(x + rowbase + (size_t)f * C_ * M_))[m4];
        ax += v.x; ay += v.y; az += v.z; aw += v.w;
    }

    __shared__ float4 red[4][32];
    red[tf][tm] = make_float4(ax, ay, az, aw);
    __syncthreads();

    if (tf == 0) {
        const float4 r1 = red[1][tm], r2 = red[2][tm], r3 = red[3][tm];
        const float inv_f = 1.0f / (float)F_;
        float4 sv;
        sv.x = (ax + r1.x + r2.x + r3.x) * inv_f;
        sv.y = (ay + r1.y + r2.y + r3.y) * inv_f;
        sv.z = (az + r1.z + r2.z + r3.z) * inv_f;
        sv.w = (aw + r1.w + r2.w + r3.w) * inv_f;
        ((float4*)(s_out + (size_t)bc * M_))[m4] = sv;

        float p = sv.x + sv.y + sv.z + sv.w;
        #pragma unroll
        for (int off = 16; off > 0; off >>= 1) p += __shfl_xor(p, off);
        if (t == 0) rpart[gid] = p;
    }
}

__global__ __launch_bounds__(256) void k2_laplace(
    const float* __restrict__ A, const float* __restrict__ phys,
    const float* __restrict__ kappa_p, const float* __restrict__ alpha_p,
    const float* __restrict__ s_in, const float* __restrict__ rpart,
    const float* __restrict__ w1, const float* __restrict__ b1,
    const float* __restrict__ w2, const float* __restrict__ b2,
    float* __restrict__ snew)
{
    __shared__ float Ab[C_ * C_];
    __shared__ float sl[C_];
    __shared__ float redA[4 * C_];
    __shared__ float degL[C_];

    const int bm = blockIdx.x;
    const int b  = bm >> 9;
    const int m  = bm & 511;
    const int t  = threadIdx.x;
    const int c  = t & 63;
    const int q  = t >> 6;
    const int h  = t & 15;
    const int a  = t >> 4;

    float r = 0.f, phv = 0.f;
    if (t < 64) {
        const float4 rp = ((const float4*)rpart)[b * C_ + t];
        const float rin = (rp.x + rp.y + rp.z + rp.w) * (1.0f / (float)M_);
        r = b2[0];
        #pragma unroll
        for (int j = 0; j < 16; ++j) {
            float hh = rin * w1[j] + b1[j];
            hh = (hh > 0.f) ? hh : (expf(hh) - 1.f);
            r += hh * w2[j];
        }
        sl[t] = s_in[((size_t)b * C_ + t) * M_ + m];
        phv   = phys[((size_t)b * C_ + t) * M_ + m];
    }

    const float4* Ap = (const float4*)(A + (size_t)bm * (C_ * C_));
    const float4 v0 = Ap[t];
    const float4 v1 = Ap[t + 256];
    const float4 v2 = Ap[t + 512];
    const float4 v3 = Ap[t + 768];
    float4* Ab4 = (float4*)Ab;
    Ab4[t]       = v0;
    Ab4[t + 256] = v1;
    Ab4[t + 512] = v2;
    Ab4[t + 768] = v3;

    float p0 = v0.x + v0.y + v0.z + v0.w;
    float p1 = v1.x + v1.y + v1.z + v1.w;
    float p2 = v2.x + v2.y + v2.z + v2.w;
    float p3 = v3.x + v3.y + v3.z + v3.w;
    #pragma unroll
    for (int mk = 1; mk < 16; mk <<= 1) {
        p0 += __shfl_xor(p0, mk);
        p1 += __shfl_xor(p1, mk);
        p2 += __shfl_xor(p2, mk);
        p3 += __shfl_xor(p3, mk);
    }
    if (h == 0) {
        degL[a]      = p0;
        degL[a + 16] = p1;
        degL[a + 32] = p2;
        degL[a + 48] = p3;
    }
    __syncthreads();

    const int j0 = q << 4;
    const float4 s4a = *(const float4*)&sl[j0];
    const float4 s4b = *(const float4*)&sl[j0 + 4];
    const float4 s4c = *(const float4*)&sl[j0 + 8];
    const float4 s4d = *(const float4*)&sl[j0 + 12];
    float ap = 0.f;
    ap += Ab[(j0 +  0) * C_ + c] * s4a.x;
    ap += Ab[(j0 +  1) * C_ + c] * s4a.y;
    ap += Ab[(j0 +  2) * C_ + c] * s4a.z;
    ap += Ab[(j0 +  3) * C_ + c] * s4a.w;
    ap += Ab[(j0 +  4) * C_ + c] * s4b.x;
    ap += Ab[(j0 +  5) * C_ + c] * s4b.y;
    ap += Ab[(j0 +  6) * C_ + c] * s4b.z;
    ap += Ab[(j0 +  7) * C_ + c] * s4b.w;
    ap += Ab[(j0 +  8) * C_ + c] * s4c.x;
    ap += Ab[(j0 +  9) * C_ + c] * s4c.y;
    ap += Ab[(j0 + 10) * C_ + c] * s4c.z;
    ap += Ab[(j0 + 11) * C_ + c] * s4c.w;
    ap += Ab[(j0 + 12) * C_ + c] * s4d.x;
    ap += Ab[(j0 + 13) * C_ + c] * s4d.y;
    ap += Ab[(j0 + 14) * C_ + c] * s4d.z;
    ap += Ab[(j0 + 15) * C_ + c] * s4d.w;
    redA[(q << 6) + c] = ap;
    __syncthreads();

    if (t < 64) {
        const float As = redA[t] + redA[64 + t] + redA[128 + t] + redA[192 + t];
        const float dg = degL[t];
        const float sval = sl[t];
        const float k    = log1pf(expf(kappa_p[0]));
        const float Ls   = dg * sval - As;
        snew[((size_t)b * C_ + t) * M_ + m] = sval - k * Ls + (r + alpha_p[0] * phv);
    }
}

__global__ __launch_bounds__(256) void k3_expand(
    const float* __restrict__ snew,
    const float* __restrict__ pw, const float* __restrict__ pb,
    float* __restrict__ out)
{
    const int n4 = (B_ * OC_ * C_ * M_) / 4;
    for (int i = blockIdx.x * blockDim.x + threadIdx.x; i < n4;
         i += gridDim.x * blockDim.x) {
        const int m4 = i & 127;
        const int c  = (i >> 7) & 63;
        const int o  = (i >> 13) & 31;
        const int b  = i >> 18;
        const float4 v = ((const float4*)snew)[(((b << 6) + c) << 7) + m4];
        const float w  = pw[o];
        const float bb = pb[o];
        vf4 r;
        r.x = v.x * w + bb; r.y = v.y * w + bb;
        r.z = v.z * w + bb; r.w = v.w * w + bb;
        __builtin_nontemporal_store(r, ((vf4*)out) + i);
    }
}

// ===========================================================================
// COOPERATIVE PATH: 1024 blocks x 256 thr (needs only 4 blocks/CU
// co-resident; VGPR budget 128, LDS 19.5 KB -> comfortably resident).
// P1 (x-mean, 2 half-rows/block) -> grid.sync -> P2 (Laplacian, 8 bm/block,
// R15-proven body) -> grid.sync -> P3 (nt-store expansion).
// ===========================================================================
__global__ __launch_bounds__(256, 4) void fused_pipeline(
    const float* __restrict__ x, const float* __restrict__ A,
    const float* __restrict__ phys,
    const float* __restrict__ kappa_p, const float* __restrict__ alpha_p,
    const float* __restrict__ w1, const float* __restrict__ b1,
    const float* __restrict__ w2, const float* __restrict__ b2,
    const float* __restrict__ pw, const float* __restrict__ pb,
    float* __restrict__ out,
    float* __restrict__ s, float* __restrict__ snew, float* __restrict__ rp2)
{
    cg::grid_group grid = cg::this_grid();

    __shared__ __align__(16) float arena[4864];   // 19456 B

    const int t   = threadIdx.x;
    const int blk = blockIdx.x;          // 0..1023

    // ============ P1: s = mean_f x; rp2[bc*2+h2] = half-row sums ============
    {
        float4* red = (float4*)arena;    // [4][64]
        const int bc = blk;              // one (b,c) row per block
        const int b  = bc >> 6;
        const int c  = bc & 63;
        const int tf = t >> 6;           // 0..3 -> f chunk of 16
        const int tm = t & 63;
        const size_t rowbase = ((size_t)b * F_ * C_ + c) * M_;

        #pragma unroll 1
        for (int h2 = 0; h2 < 2; ++h2) {
            const int m4 = (h2 << 6) + tm;   // float4 col 0..127
            float ax = 0.f, ay = 0.f, az = 0.f, aw = 0.f;
            #pragma unroll 8
            for (int j = 0; j < 16; ++j) {
                const int f = (tf << 4) + j;
                const float4 v =
                    ((const float4*)(x + rowbase + (size_t)f * C_ * M_))[m4];
                ax += v.x; ay += v.y; az += v.z; aw += v.w;
            }
            red[(tf << 6) + tm] = make_float4(ax, ay, az, aw);
            __syncthreads();

            if (tf == 0) {               // threads 0..63 = wave 0
                const float4 r1 = red[64 + tm], r2 = red[128 + tm],
                             r3 = red[192 + tm];
                const float inv_f = 1.0f / (float)F_;
                float4 sv;
                sv.x = (ax + r1.x + r2.x + r3.x) * inv_f;
                sv.y = (ay + r1.y + r2.y + r3.y) * inv_f;
                sv.z = (az + r1.z + r2.z + r3.z) * inv_f;
                sv.w = (aw + r1.w + r2.w + r3.w) * inv_f;
                ((float4*)(s + (size_t)bc * M_))[m4] = sv;

                float p = sv.x + sv.y + sv.z + sv.w;
                #pragma unroll
                for (int off = 32; off > 0; off >>= 1) p += __shfl_xor(p, off);
                if (t == 0) rp2[bc * 2 + h2] = p;
            }
            __syncthreads();             // red[] reuse fence
        }
    }

    grid.sync();

    // ============ P2: Laplacian, 8 bm per block (R15 body) ============
    {
        float* Ab   = arena;             // 4096 f
        float* slb  = arena + 4096;      // 2 x 64 (parity)
        float* redA = arena + 4224;      // 2 x 256
        float* degL = arena + 4736;      // 2 x 64

        const int c = t & 63;
        const int q = t >> 6;
        const int h = t & 15;
        const int a = t >> 4;

        const int bm0 = blk << 3;        // 8 consecutive (b,m), same b
        const int b   = bm0 >> 9;

        const float kcoef = log1pf(expf(kappa_p[0]));
        const float al    = alpha_p[0];

        float r_c = 0.f;
        if (t < 64) {
            const float2 rp = ((const float2*)rp2)[b * C_ + t];
            const float rin = (rp.x + rp.y) * (1.0f / (float)M_);
            r_c = b2[0];
            #pragma unroll
            for (int j = 0; j < 16; ++j) {
                float hh = rin * w1[j] + b1[j];
                hh = (hh > 0.f) ? hh : (expf(hh) - 1.f);
                r_c += hh * w2[j];
            }
        }

        #pragma unroll 1
        for (int i = 0; i < 8; ++i) {
            const int bm  = bm0 + i;
            const int m   = bm & 511;
            const int par = i & 1;
            float* sl = slb + par * 64;

            float phv = 0.f;
            if (t < 64) {
                sl[t] = s[((size_t)b * C_ + t) * M_ + m];
                phv   = phys[((size_t)b * C_ + t) * M_ + m];
            }

            const float4* Ap = (const float4*)(A + (size_t)bm * (C_ * C_));
            const float4 v0 = Ap[t];
            const float4 v1 = Ap[t + 256];
            const float4 v2 = Ap[t + 512];
            const float4 v3 = Ap[t + 768];
            float4* Ab4 = (float4*)Ab;
            Ab4[t]       = v0;
            Ab4[t + 256] = v1;
            Ab4[t + 512] = v2;
            Ab4[t + 768] = v3;

            float p0 = v0.x + v0.y + v0.z + v0.w;
            float p1 = v1.x + v1.y + v1.z + v1.w;
            float p2 = v2.x + v2.y + v2.z + v2.w;
            float p3 = v3.x + v3.y + v3.z + v3.w;
            #pragma unroll
            for (int mk = 1; mk < 16; mk <<= 1) {
                p0 += __shfl_xor(p0, mk);
                p1 += __shfl_xor(p1, mk);
                p2 += __shfl_xor(p2, mk);
                p3 += __shfl_xor(p3, mk);
            }
            if (h == 0) {
                degL[par * 64 + a]      = p0;
                degL[par * 64 + a + 16] = p1;
                degL[par * 64 + a + 32] = p2;
                degL[par * 64 + a + 48] = p3;
            }
            __syncthreads();             // Ab, sl, degL visible

            const int j0 = q << 4;
            const float4 s4a = *(const float4*)&sl[j0];
            const float4 s4b = *(const float4*)&sl[j0 + 4];
            const float4 s4c = *(const float4*)&sl[j0 + 8];
            const float4 s4d = *(const float4*)&sl[j0 + 12];
            float ap = 0.f;
            ap += Ab[(j0 +  0) * C_ + c] * s4a.x;
            ap += Ab[(j0 +  1) * C_ + c] * s4a.y;
            ap += Ab[(j0 +  2) * C_ + c] * s4a.z;
            ap += Ab[(j0 +  3) * C_ + c] * s4a.w;
            ap += Ab[(j0 +  4) * C_ + c] * s4b.x;
            ap += Ab[(j0 +  5) * C_ + c] * s4b.y;
            ap += Ab[(j0 +  6) * C_ + c] * s4b.z;
            ap += Ab[(j0 +  7) * C_ + c] * s4b.w;
            ap += Ab[(j0 +  8) * C_ + c] * s4c.x;
            ap += Ab[(j0 +  9) * C_ + c] * s4c.y;
            ap += Ab[(j0 + 10) * C_ + c] * s4c.z;
            ap += Ab[(j0 + 11) * C_ + c] * s4c.w;
            ap += Ab[(j0 + 12) * C_ + c] * s4d.x;
            ap += Ab[(j0 + 13) * C_ + c] * s4d.y;
            ap += Ab[(j0 + 14) * C_ + c] * s4d.z;
            ap += Ab[(j0 + 15) * C_ + c] * s4d.w;
            redA[par * 256 + (q << 6) + c] = ap;
            __syncthreads();             // redA visible; Ab free next iter

            if (t < 64) {
                const float* rA = redA + par * 256;
                const float As = rA[t] + rA[64 + t] + rA[128 + t] + rA[192 + t];
                const float dg = degL[par * 64 + t];
                const float sval = sl[t];
                snew[((size_t)b * C_ + t) * M_ + m] =
                    sval - kcoef * (dg * sval - As) + (r_c + al * phv);
            }
        }
    }

    grid.sync();

    // ============ P3: 32-channel nt-store expansion ============
    {
        const int n4 = (B_ * OC_ * C_ * M_) / 4;     // 4,194,304
        const int stride = gridDim.x * blockDim.x;   // 262,144
        for (int i = blk * blockDim.x + t; i < n4; i += stride) {
            const int m4 = i & 127;
            const int c  = (i >> 7) & 63;
            const int o  = (i >> 13) & 31;
            const int b  = i >> 18;
            const float4 v = ((const float4*)snew)[(((b << 6) + c) << 7) + m4];
            const float w  = pw[o];
            const float bb = pb[o];
            vf4 r;
            r.x = v.x * w + bb; r.y = v.y * w + bb;
            r.z = v.z * w + bb; r.w = v.w * w + bb;
            __builtin_nontemporal_store(r, ((vf4*)out) + i);
        }
    }
}

extern "C" void kernel_launch(void* const* d_in, const int* in_sizes, int n_in,
                              void* d_out, int out_size, void* d_ws, size_t ws_size,
                              hipStream_t stream)
{
    const float* x     = (const float*)d_in[0];
    const float* A     = (const float*)d_in[1];
    const float* phys  = (const float*)d_in[2];
    const float* kappa = (const float*)d_in[3];
    const float* alpha = (const float*)d_in[4];
    const float* w1    = (const float*)d_in[5];
    const float* b1    = (const float*)d_in[6];
    const float* w2    = (const float*)d_in[7];
    const float* b2    = (const float*)d_in[8];
    const float* pw    = (const float*)d_in[9];
    const float* pb    = (const float*)d_in[10];
    float* out = (float*)d_out;

    float* ws     = (float*)d_ws;
    float* s      = ws;                              // B*C*M
    float* snew   = ws + (size_t)B_ * C_ * M_;       // B*C*M
    float* rpart4 = ws + (size_t)2 * B_ * C_ * M_;   // B*C*4 (fallback)
    float* rp2    = rpart4 + (size_t)B_ * C_ * 4;    // B*C*2 (coop)

    void* args[] = {
        (void*)&x, (void*)&A, (void*)&phys, (void*)&kappa, (void*)&alpha,
        (void*)&w1, (void*)&b1, (void*)&w2, (void*)&b2, (void*)&pw, (void*)&pb,
        (void*)&out, (void*)&s, (void*)&snew, (void*)&rp2
    };
    hipError_t err = hipLaunchCooperativeKernel((const void*)fused_pipeline,
                                                dim3(1024), dim3(256), args,
                                                0, stream);
    if (err != hipSuccess) {
        // deterministic fallback: proven R15 3-kernel path (65.2 us)
        k1_mean<<<B_ * C_ * 4, 128, 0, stream>>>(x, s, rpart4);
        k2_laplace<<<B_ * M_, 256, 0, stream>>>(A, phys, kappa, alpha, s, rpart4,
                                                w1, b1, w2, b2, snew);
        k3_expand<<<2048, 256, 0, stream>>>(snew, pw, pb, out);
    }
}

// Round 18
// 64.238 us; speedup vs baseline: 4.9736x; 4.9736x over previous
//
#include <hip/hip_runtime.h>
#include <math.h>

#define B_  16
#define F_  64
#define C_  64
#define M_  512
#define OC_ 32

typedef float vf4 __attribute__((ext_vector_type(4)));   // clang-native for nt st

// ---------------------------------------------------------------------------
// k1: R15 production version (plain x loads, m-split 4-ways). At its floor.
// ---------------------------------------------------------------------------
__global__ __launch_bounds__(128, 6) void k1_mean(
    const float* __restrict__ x,
    float* __restrict__ s_out, float* __restrict__ rpart)
{
    const int gid = blockIdx.x;        // bc*4 + q
    const int q   = gid & 3;
    const int bc  = gid >> 2;
    const int b   = bc >> 6;
    const int c   = bc & 63;
    const int t   = threadIdx.x;
    const int tf  = t >> 5;
    const int tm  = t & 31;
    const int m4  = (q << 5) + tm;

    const size_t rowbase = ((size_t)b * F_ * C_ + c) * M_;
    float ax = 0.f, ay = 0.f, az = 0.f, aw = 0.f;
    #pragma unroll 8
    for (int j = 0; j < 16; ++j) {
        const int f = (tf << 4) + j;
        const float4 v = ((const float4*)(x + rowbase + (size_t)f * C_ * M_))[m4];
        ax += v.x; ay += v.y; az += v.z; aw += v.w;
    }

    __shared__ float4 red[4][32];
    red[tf][tm] = make_float4(ax, ay, az, aw);
    __syncthreads();

    if (tf == 0) {
        const float4 r1 = red[1][tm], r2 = red[2][tm], r3 = red[3][tm];
        const float inv_f = 1.0f / (float)F_;
        float4 sv;
        sv.x = (ax + r1.x + r2.x + r3.x) * inv_f;
        sv.y = (ay + r1.y + r2.y + r3.y) * inv_f;
        sv.z = (az + r1.z + r2.z + r3.z) * inv_f;
        sv.w = (aw + r1.w + r2.w + r3.w) * inv_f;
        ((float4*)(s_out + (size_t)bc * M_))[m4] = sv;

        float p = sv.x + sv.y + sv.z + sv.w;
        #pragma unroll
        for (int off = 16; off > 0; off >>= 1) p += __shfl_xor(p, off);
        if (t == 0) rpart[gid] = p;
    }
}

// ---------------------------------------------------------------------------
// k2f: fused Laplacian + 32-channel expansion. Block = (b, 16-m window),
// 1024 threads (16 waves), 2 blocks/CU = 32 waves/CU (full occupancy).
// Double-buffered A tiles: regs->LDS, next tile's loads issued before
// current tile's compute; deg computed from the staging REGISTERS (shfl
// over the 16 threads of each row) before they are consumed — no extra
// waits. snew lives only in LDS; epilogue writes out with full-64B-line
// nt float4 stores. Deletes k3 launch, its ramp, and the snew roundtrip.
// LDS 49 KB. All LDS access patterns <=2-way bank aliased (free).
// ---------------------------------------------------------------------------
__global__ __launch_bounds__(1024, 8) void k2_fused(
    const float* __restrict__ A, const float* __restrict__ phys,
    const float* __restrict__ kappa_p, const float* __restrict__ alpha_p,
    const float* __restrict__ s_in, const float* __restrict__ rpart,
    const float* __restrict__ w1, const float* __restrict__ b1,
    const float* __restrict__ w2, const float* __restrict__ b2,
    const float* __restrict__ pw, const float* __restrict__ pb,
    float* __restrict__ out)
{
    __shared__ float Ab[2][4096];      // 32 KB, linear [row j][col c]
    __shared__ float sl[16 * 68];      // sl[mi*68 + j] = s[b, j, m0+mi]
    __shared__ float ph[16 * 68];      // phys, same layout
    __shared__ float snl[64 * 17];     // snl[c*17 + mi]
    __shared__ float redA[16 * 64];    // per-tile As partials
    __shared__ float degL[C_];

    const int t   = threadIdx.x;       // 0..1023
    const int blk = blockIdx.x;        // b*32 + window
    const int b   = blk >> 5;
    const int m0  = (blk & 31) << 4;

    // ---- stage s/phys window: thread (c = t>>4, mi = t&15) ----
    {
        const int cc = t >> 4;
        const int mi = t & 15;
        const size_t g = ((size_t)(b * C_ + cc)) * M_ + m0 + mi;
        sl[mi * 68 + cc] = s_in[g];
        ph[mi * 68 + cc] = phys[g];
    }

    // ---- r-MLP (wave 0 keeps r in a register) ----
    float r_c = 0.f;
    if (t < 64) {
        const float4 rp = ((const float4*)rpart)[b * C_ + t];
        const float rin = (rp.x + rp.y + rp.z + rp.w) * (1.0f / (float)M_);
        r_c = b2[0];
        #pragma unroll
        for (int j = 0; j < 16; ++j) {
            float hh = rin * w1[j] + b1[j];
            hh = (hh > 0.f) ? hh : (expf(hh) - 1.f);   // ELU(alpha=1)
            r_c += hh * w2[j];
        }
    }

    // ---- tile 0: regs -> LDS buf 0 ----
    const float* Abase = A + (size_t)(b * M_ + m0) * (C_ * C_);
    float4 v = ((const float4*)Abase)[t];    // row t>>4, cols (t&15)*4..+3
    ((float4*)Ab[0])[t] = v;
    __syncthreads();

    const float kcoef = log1pf(expf(kappa_p[0]));      // softplus(kappa)
    const float al    = alpha_p[0];
    const int c   = t & 63;
    const int g   = t >> 6;            // wave id: j-group 4g..4g+3
    const int row = t >> 4;            // staging row for deg
    const int h   = t & 15;

    #pragma unroll 1
    for (int i = 0; i < 16; ++i) {
        const int cur = i & 1;

        // prefetch next tile into regs (no wait until after B1)
        float4 vn;
        if (i < 15)
            vn = ((const float4*)(Abase + (size_t)(i + 1) * (C_ * C_)))[t];

        // deg of tile i from current regs: 16 threads per row, shfl h-group
        float p = v.x + v.y + v.z + v.w;
        p += __shfl_xor(p, 1);
        p += __shfl_xor(p, 2);
        p += __shfl_xor(p, 4);
        p += __shfl_xor(p, 8);
        if (h == 0) degL[row] = p;

        // As partial: wave g covers j = 4g..4g+3 at col c (conflict-free)
        const float s0 = sl[i * 68 + 4 * g + 0];   // wave-broadcast reads
        const float s1 = sl[i * 68 + 4 * g + 1];
        const float s2 = sl[i * 68 + 4 * g + 2];
        const float s3 = sl[i * 68 + 4 * g + 3];
        const float ap = Ab[cur][(4 * g + 0) * 64 + c] * s0
                       + Ab[cur][(4 * g + 1) * 64 + c] * s1
                       + Ab[cur][(4 * g + 2) * 64 + c] * s2
                       + Ab[cur][(4 * g + 3) * 64 + c] * s3;
        redA[g * 64 + c] = ap;
        __syncthreads();               // B1: redA/degL visible

        if (t < 64) {                  // wave 0 combines + snl write
            float As = 0.f;
            #pragma unroll
            for (int gg = 0; gg < 16; ++gg) As += redA[gg * 64 + t];
            const float dg   = degL[t];
            const float sval = sl[i * 68 + t];
            const float pv   = ph[i * 68 + t];
            snl[t * 17 + i] = sval - kcoef * (dg * sval - As) + (r_c + al * pv);
        }
        if (i < 15) {                  // other waves: stage next tile
            ((float4*)Ab[cur ^ 1])[t] = vn;
            v = vn;
        }
        __syncthreads();               // B2: Ab[next] + snl(i) ready
    }

    // ---- epilogue: out[b,o,c,m0..m0+15], full-64B-line nt stores ----
    #pragma unroll
    for (int i = 0; i < 8; ++i) {
        const int idx = (i << 10) + t;     // 0..8191 = o*256 + c*4 + mq
        const int mq  = idx & 3;
        const int cc  = (idx >> 2) & 63;
        const int o   = idx >> 8;
        const float w  = pw[o];
        const float bb = pb[o];
        vf4 ov;
        ov.x = snl[cc * 17 + mq * 4 + 0] * w + bb;
        ov.y = snl[cc * 17 + mq * 4 + 1] * w + bb;
        ov.z = snl[cc * 17 + mq * 4 + 2] * w + bb;
        ov.w = snl[cc * 17 + mq * 4 + 3] * w + bb;
        __builtin_nontemporal_store(ov,
            (vf4*)(out + (((size_t)(b * OC_ + o)) * C_ + cc) * M_ + m0 + mq * 4));
    }
}

extern "C" void kernel_launch(void* const* d_in, const int* in_sizes, int n_in,
                              void* d_out, int out_size, void* d_ws, size_t ws_size,
                              hipStream_t stream)
{
    const float* x     = (const float*)d_in[0];
    const float* A     = (const float*)d_in[1];
    const float* phys  = (const float*)d_in[2];
    const float* kappa = (const float*)d_in[3];
    const float* alpha = (const float*)d_in[4];
    const float* w1    = (const float*)d_in[5];
    const float* b1    = (const float*)d_in[6];
    const float* w2    = (const float*)d_in[7];
    const float* b2    = (const float*)d_in[8];
    const float* pw    = (const float*)d_in[9];
    const float* pb    = (const float*)d_in[10];
    float* out = (float*)d_out;

    float* ws    = (float*)d_ws;
    float* s     = ws;                            // B*C*M
    float* rpart = ws + (size_t)B_ * C_ * M_;     // B*C*4 (16B-aligned)

    k1_mean<<<B_ * C_ * 4, 128, 0, stream>>>(x, s, rpart);
    k2_fused<<<B_ * (M_ / 16), 1024, 0, stream>>>(A, phys, kappa, alpha, s, rpart,
                                                  w1, b1, w2, b2, pw, pb, out);
}